// Round 17
// baseline (208.327 us; speedup 1.0000x reference)
//
#include <hip/hip_runtime.h>
#include <hip/hip_bf16.h>

// N=50000 nodes, E=300000 edges, C=128.
// W_comb = W_edge@W_gcn = [W1;W2;W3].
//   P1 = x@W1 + b_comb, P2 = x@W2          (bf16, P2-PERMUTED col layout)
//   xws[e] = (ea[e]@W3 + P1[src]+P2[dst]) * dinv_e[e]   (bf16, P2-PERMUTED)
//   agg[v] = sum_{dst(j)=v} xws[j]          (bf16, P2-PERMUTED)
//   out[e] = leaky( dinv_e[e]*(agg[src[e]] + xws[e]) + b_gcn )   (f32, canonical)
// p2(c) = ((c>>5)&3)*32 + ((c>>2)&3)*8 + ((c>>4)&1)*4 + (c&3).
// gemm3: 512 threads (8 waves) share ONE 32KB W-stage — tests the blocks/CU
// residency cap theory (R10's spill came from the (512,6) VGPR cap, not width).

typedef __bf16 bf16x8 __attribute__((ext_vector_type(8)));
typedef float  f32x4  __attribute__((ext_vector_type(4)));

#define C_DIM 128

__device__ __forceinline__ float bfu_lo(unsigned u) { return __uint_as_float(u << 16); }
__device__ __forceinline__ float bfu_hi(unsigned u) { return __uint_as_float(u & 0xffff0000u); }
__device__ __forceinline__ unsigned bf16_bits(float f) {
    __bf16 h = (__bf16)f;
    return (unsigned)__builtin_bit_cast(unsigned short, h);
}

// ---------------- K0: fused {W_comb fragment build + b_comb} and {in-degree}
__global__ void k_wcomb_indeg(const float* __restrict__ W_edge, const float* __restrict__ W_gcn,
                              const float* __restrict__ b_edge,
                              __bf16* __restrict__ Wf, float* __restrict__ b_comb,
                              const int* __restrict__ dst, int E, int* __restrict__ indeg) {
    if ((int)blockIdx.x < 192) {
        int idx = blockIdx.x * 256 + threadIdx.x;        // 384*128 outputs
        if (idx < 384 * 128) {
            int k = idx >> 7, c = idx & 127;
            float s = 0.f;
            for (int m = 0; m < 128; ++m) s += W_edge[k * 128 + m] * W_gcn[m * 128 + c];
            int ks = k >> 5, kc8 = (k >> 3) & 3, j = k & 7;
            int col16 = c >> 4, c15 = c & 15;
            Wf[(size_t)(((ks * 8 + col16) * 64) + kc8 * 16 + c15) * 8 + j] = (__bf16)s;
        }
        if (blockIdx.x == 0 && threadIdx.x < 128) {
            int c = threadIdx.x;
            float s = 0.f;
            for (int m = 0; m < 128; ++m) s += b_edge[m] * W_gcn[m * 128 + c];
            b_comb[c] = s;
        }
        return;
    }
    int e = ((int)blockIdx.x - 192) * 256 + threadIdx.x;
    if (e < E) atomicAdd(&indeg[dst[e]], 1);
}

// ---------------- K2a: per-block sums of indeg (1024-elem blocks)
__global__ void k_scan_bsum(const int* __restrict__ indeg, int n, int* __restrict__ bsum) {
    __shared__ int ws[16];
    int i = blockIdx.x * 1024 + threadIdx.x;
    int v = (i < n) ? indeg[i] : 0;
    int lane = threadIdx.x & 63, wid = threadIdx.x >> 6;
    for (int off = 32; off; off >>= 1) v += __shfl_down(v, off);
    if (lane == 0) ws[wid] = v;
    __syncthreads();
    if (threadIdx.x < 16) {
        int s = ws[threadIdx.x];
        for (int off = 8; off; off >>= 1) s += __shfl_down(s, off);
        if (threadIdx.x == 0) bsum[blockIdx.x] = s;
    }
}

// ---------------- K2b: finalize exclusive scan (integrates top-level scan of bsum)
__global__ void k_scan_fin(const int* __restrict__ indeg, int n, const int* __restrict__ bsum,
                           int nb, int* __restrict__ ptr, int* __restrict__ cursor) {
    __shared__ int wsum[16];
    __shared__ int s_boff, s_total;
    int lane = threadIdx.x & 63, wid = threadIdx.x >> 6;
    if (threadIdx.x < 64) {
        int v = (lane < nb) ? bsum[lane] : 0;
        int incl = v;
        for (int off = 1; off < 64; off <<= 1) {
            int t = __shfl_up(incl, off);
            if (lane >= off) incl += t;
        }
        if (lane == (int)blockIdx.x) s_boff = incl - v;
        if (lane == 63) s_total = incl;
    }
    int i = blockIdx.x * 1024 + threadIdx.x;
    int v = (i < n) ? indeg[i] : 0;
    int incl = v;
    for (int off = 1; off < 64; off <<= 1) {
        int t = __shfl_up(incl, off);
        if (lane >= off) incl += t;
    }
    if (lane == 63) wsum[wid] = incl;
    __syncthreads();
    if (wid == 0 && lane < 16) {
        int s = wsum[lane];
        for (int off = 1; off < 16; off <<= 1) {
            int t = __shfl_up(s, off);
            if (lane >= off) s += t;
        }
        wsum[lane] = s;
    }
    __syncthreads();
    int woff = wid ? wsum[wid - 1] : 0;
    if (i < n) {
        int ex = s_boff + woff + incl - v;
        ptr[i] = ex;
        cursor[i] = ex;
    }
    if (blockIdx.x == 0 && threadIdx.x == 0) ptr[n] = s_total;
}

// ---------------- K3+K4a fused: {CSR place + dinv_e} and {P1 = x@W1 + b_comb, P2 = x@W2}
__global__ __launch_bounds__(256) void k_place_p12(
    const int* __restrict__ src, const int* __restrict__ dst, int E, int nbPlace,
    int* __restrict__ cursor, int* __restrict__ adj,
    const int* __restrict__ indeg, float* __restrict__ dinv_e,
    const float* __restrict__ x, const __bf16* __restrict__ Wf,
    const float* __restrict__ b_comb,
    __bf16* __restrict__ P1, __bf16* __restrict__ P2, int M) {

    __shared__ __align__(16) __bf16 As[64 * 136];

    if ((int)blockIdx.x < nbPlace) {
        int e = blockIdx.x * 256 + threadIdx.x;
        if (e < E) {
            int pos = atomicAdd(&cursor[dst[e]], 1);
            adj[pos] = e;
            dinv_e[e] = rsqrtf(1.0f + (float)indeg[src[e]]);
        }
        return;
    }

    const int tid = threadIdx.x;
    const int mbase = ((int)blockIdx.x - nbPlace) * 64;
    const int r = tid >> 2, q = tid & 3;
    const int m_r = mbase + r;
    const int m_rc = (m_r < M) ? m_r : 0;
    const float* rp = x + (size_t)m_rc * C_DIM;

#pragma unroll
    for (int s4 = 0; s4 < 4; ++s4) {
        const float* p = rp + s4 * 32 + q * 8;
        float4 f0 = *(const float4*)p;
        float4 f1 = *(const float4*)(p + 4);
        bf16x8 h;
        h[0] = (__bf16)f0.x; h[1] = (__bf16)f0.y; h[2] = (__bf16)f0.z; h[3] = (__bf16)f0.w;
        h[4] = (__bf16)f1.x; h[5] = (__bf16)f1.y; h[6] = (__bf16)f1.z; h[7] = (__bf16)f1.w;
        int u = s4 * 4 + q;                              // 16B unit 0..15
        *(bf16x8*)&As[r * 128 + ((u ^ (r & 7)) << 3)] = h;
    }
    __syncthreads();

    const int lane = tid & 63, wid = tid >> 6;
    const int wr = wid >> 1, wc = wid & 1;
    const int kc8 = lane >> 4;
    const int arow0 = wr * 32 + (lane & 15);
    const int arow1 = arow0 + 16;
    const __bf16* wfb = Wf + ((size_t)(wc * 4) * 64 + lane) * 8;

    f32x4 acc1[2][4] = {};
    f32x4 acc2[2][4] = {};

#pragma unroll
    for (int ks = 0; ks < 4; ++ks) {
        int u = ks * 4 + kc8;
        bf16x8 a0 = *(const bf16x8*)&As[arow0 * 128 + ((u ^ (arow0 & 7)) << 3)];
        bf16x8 a1 = *(const bf16x8*)&As[arow1 * 128 + ((u ^ (arow1 & 7)) << 3)];
#pragma unroll
        for (int n = 0; n < 4; ++n) {
            bf16x8 b1 = *(const bf16x8*)&wfb[(size_t)(ks * 8 + n) * 64 * 8];
            bf16x8 b2 = *(const bf16x8*)&wfb[(size_t)((ks + 4) * 8 + n) * 64 * 8];
            acc1[0][n] = __builtin_amdgcn_mfma_f32_16x16x32_bf16(a0, b1, acc1[0][n], 0, 0, 0);
            acc1[1][n] = __builtin_amdgcn_mfma_f32_16x16x32_bf16(a1, b1, acc1[1][n], 0, 0, 0);
            acc2[0][n] = __builtin_amdgcn_mfma_f32_16x16x32_bf16(a0, b2, acc2[0][n], 0, 0, 0);
            acc2[1][n] = __builtin_amdgcn_mfma_f32_16x16x32_bf16(a1, b2, acc2[1][n], 0, 0, 0);
        }
    }

#pragma unroll
    for (int pass = 0; pass < 2; ++pass) {
        __syncthreads();
#pragma unroll
        for (int m = 0; m < 2; ++m)
#pragma unroll
            for (int j = 0; j < 4; ++j) {
                int row = wr * 32 + m * 16 + (lane >> 4) * 4 + j;
#pragma unroll
                for (int n = 0; n < 4; ++n) {
                    int c = wc * 64 + n * 16 + (lane & 15);
                    // p2(c): unit-transposed permutation
                    int p = ((c >> 5) & 3) * 32 + ((c >> 2) & 3) * 8 + ((c >> 4) & 1) * 4 + (c & 3);
                    float v = pass == 0 ? acc1[m][n][j] + b_comb[c] : acc2[m][n][j];
                    As[row * 136 + p] = (__bf16)v;
                }
            }
        __syncthreads();
        if (m_r < M) {
            __bf16* outp = (pass == 0 ? P1 : P2) + (size_t)m_r * C_DIM + q * 32;
#pragma unroll
            for (int i = 0; i < 4; ++i)
                *(bf16x8*)(outp + i * 8) = *(const bf16x8*)&As[r * 136 + q * 32 + i * 8];
        }
    }
}

// ---------------- K4b: xws[e] = (ea[e]@W3 + P1[src]+P2[dst]) * dinv_e  (p2 layout)
// 512 threads = 8 waves share ONE 32KB W-stage; NO min-wave bound (no VGPR cap).
// Swapped-operand, wave-autonomous, 2 staggered tiles/wave, register epilogue.
__global__ __launch_bounds__(512) void k_gemm3(
    const float* __restrict__ ea, const __bf16* __restrict__ Wf,
    const __bf16* __restrict__ P1, const __bf16* __restrict__ P2,
    const int* __restrict__ src, const int* __restrict__ dst,
    const float* __restrict__ dinv_e, __bf16* __restrict__ xws, int E) {

    __shared__ __align__(16) __bf16 Wlds[16384];       // 32KB: frags (ks 0..3)x(n 0..7)

    const int tid = threadIdx.x;
    // ---- W-stage first (L2-hot 32KB), one fast barrier (2048 uint4 / 512 thr)
    {
        const uint4* wsrc = (const uint4*)Wf + 4096;    // ksAbs 8..11 slice
        uint4* wdst = (uint4*)Wlds;
#pragma unroll
        for (int i = 0; i < 4; ++i) wdst[tid + i * 512] = wsrc[tid + i * 512];
    }
    __syncthreads();

    const int wid = tid >> 6, lane = tid & 63;
    const int e15 = lane & 15, q = lane >> 4;
    const int eb0 = blockIdx.x * 256 + wid * 32;
    const int eb1 = eb0 + 16;
    if (eb0 >= E) return;
    const bool has1 = (eb1 < E);

    const int e0 = eb0 + e15;
    const int e0c = (e0 < E) ? e0 : E - 1;
    const int e1 = eb1 + e15;
    const int e1c = (e1 < E) ? e1 : E - 1;

    // ---- indices + dinv (both tiles); dinv_e is a coalesced load
    const int s0 = src[e0c], d0 = dst[e0c];
    const float di0 = dinv_e[e0c];
    int s1 = s0, d1 = d0;
    float di1 = di0;
    if (has1) { s1 = src[e1c]; d1 = dst[e1c]; di1 = dinv_e[e1c]; }

    // ---- issue ea0, P0, ea1
    const float* ap0 = ea + (size_t)e0c * C_DIM + q * 8;
    float4 fa[8];
#pragma unroll
    for (int ks = 0; ks < 4; ++ks) {
        fa[2 * ks]     = *(const float4*)(ap0 + ks * 32);
        fa[2 * ks + 1] = *(const float4*)(ap0 + ks * 32 + 4);
    }
    // p2 layout: unit m of this lane at elem q*8 + m*32 (one full 64B line/instr)
    uint4 hA1[4], hA2[4];
    {
        const uint4* p1 = (const uint4*)(P1 + (size_t)s0 * C_DIM + q * 8);
        const uint4* p2 = (const uint4*)(P2 + (size_t)d0 * C_DIM + q * 8);
#pragma unroll
        for (int m = 0; m < 4; ++m) { hA1[m] = p1[m * 4]; hA2[m] = p2[m * 4]; }
    }
    const float* ap1 = ea + (size_t)e1c * C_DIM + q * 8;
    float4 fb[8];
    if (has1) {
#pragma unroll
        for (int ks = 0; ks < 4; ++ks) {
            fb[2 * ks]     = *(const float4*)(ap1 + ks * 32);
            fb[2 * ks + 1] = *(const float4*)(ap1 + ks * 32 + 4);
        }
    }

    // ---- tile0 MFMA
    f32x4 acc[8] = {};
#pragma unroll
    for (int ks = 0; ks < 4; ++ks) {
        float4 f0 = fa[2 * ks], f1 = fa[2 * ks + 1];
        bf16x8 b;
        b[0] = (__bf16)f0.x; b[1] = (__bf16)f0.y; b[2] = (__bf16)f0.z; b[3] = (__bf16)f0.w;
        b[4] = (__bf16)f1.x; b[5] = (__bf16)f1.y; b[6] = (__bf16)f1.z; b[7] = (__bf16)f1.w;
#pragma unroll
        for (int n = 0; n < 8; ++n) {
            bf16x8 a = *(const bf16x8*)&Wlds[(size_t)((ks * 8 + n) * 64 + lane) * 8];
            acc[n] = __builtin_amdgcn_mfma_f32_16x16x32_bf16(a, b, acc[n], 0, 0, 0);
        }
    }

    // ---- issue P gathers for tile1 (hide under epilogue0 + mfma1)
    uint4 hB1[4], hB2[4];
    if (has1) {
        const uint4* p1 = (const uint4*)(P1 + (size_t)s1 * C_DIM + q * 8);
        const uint4* p2 = (const uint4*)(P2 + (size_t)d1 * C_DIM + q * 8);
#pragma unroll
        for (int m = 0; m < 4; ++m) { hB1[m] = p1[m * 4]; hB2[m] = p2[m * 4]; }
    }

    // ---- epilogue0 (p2 layout: unit m stored at elem q*8 + m*32)
    if (e0 < E) {
        __bf16* op = xws + (size_t)e0 * C_DIM + q * 8;
#pragma unroll
        for (int m = 0; m < 4; ++m) {
            bf16x8 h1 = __builtin_bit_cast(bf16x8, hA1[m]);
            bf16x8 h2 = __builtin_bit_cast(bf16x8, hA2[m]);
            uint4 u;
            unsigned w[4];
#pragma unroll
            for (int hw = 0; hw < 4; ++hw) {
                int n = 2 * m + (hw >> 1);
                int j0 = (hw & 1) * 2;
                float v0 = (acc[n][j0]     + (float)h1[(hw >> 1) * 4 + j0]     + (float)h2[(hw >> 1) * 4 + j0])     * di0;
                float v1 = (acc[n][j0 + 1] + (float)h1[(hw >> 1) * 4 + j0 + 1] + (float)h2[(hw >> 1) * 4 + j0 + 1]) * di0;
                w[hw] = bf16_bits(v0) | (bf16_bits(v1) << 16);
            }
            u.x = w[0]; u.y = w[1]; u.z = w[2]; u.w = w[3];
            *(uint4*)(op + m * 32) = u;
        }
    }

    if (!has1) return;

    // ---- tile1 MFMA
    f32x4 acc2[8] = {};
#pragma unroll
    for (int ks = 0; ks < 4; ++ks) {
        float4 f0 = fb[2 * ks], f1 = fb[2 * ks + 1];
        bf16x8 b;
        b[0] = (__bf16)f0.x; b[1] = (__bf16)f0.y; b[2] = (__bf16)f0.z; b[3] = (__bf16)f0.w;
        b[4] = (__bf16)f1.x; b[5] = (__bf16)f1.y; b[6] = (__bf16)f1.z; b[7] = (__bf16)f1.w;
#pragma unroll
        for (int n = 0; n < 8; ++n) {
            bf16x8 a = *(const bf16x8*)&Wlds[(size_t)((ks * 8 + n) * 64 + lane) * 8];
            acc2[n] = __builtin_amdgcn_mfma_f32_16x16x32_bf16(a, b, acc2[n], 0, 0, 0);
        }
    }

    // ---- epilogue1
    if (e1 < E) {
        __bf16* op = xws + (size_t)e1 * C_DIM + q * 8;
#pragma unroll
        for (int m = 0; m < 4; ++m) {
            bf16x8 h1 = __builtin_bit_cast(bf16x8, hB1[m]);
            bf16x8 h2 = __builtin_bit_cast(bf16x8, hB2[m]);
            uint4 u;
            unsigned w[4];
#pragma unroll
            for (int hw = 0; hw < 4; ++hw) {
                int n = 2 * m + (hw >> 1);
                int j0 = (hw & 1) * 2;
                float v0 = (acc2[n][j0]     + (float)h1[(hw >> 1) * 4 + j0]     + (float)h2[(hw >> 1) * 4 + j0])     * di1;
                float v1 = (acc2[n][j0 + 1] + (float)h1[(hw >> 1) * 4 + j0 + 1] + (float)h2[(hw >> 1) * 4 + j0 + 1]) * di1;
                w[hw] = bf16_bits(v0) | (bf16_bits(v1) << 16);
            }
            u.x = w[0]; u.y = w[1]; u.z = w[2]; u.w = w[3];
            *(uint4*)(op + m * 32) = u;
        }
    }
}

// ---------------- K5: agg[v] = sum over incoming edges (unroll-2, layout-agnostic)
__global__ void k_agg(const __bf16* __restrict__ xws, const int* __restrict__ ptr,
                      const int* __restrict__ adj, __bf16* __restrict__ agg, int Nn) {
    int v = blockIdx.x * 4 + (threadIdx.x >> 6);
    if (v >= Nn) return;
    int c = threadIdx.x & 63;           // permuted positions 2c / 2c+1
    int b0 = ptr[v], b1 = ptr[v + 1];
    float s0 = 0.f, s1 = 0.f, t0 = 0.f, t1 = 0.f;
    int t = b0;
    for (; t + 2 <= b1; t += 2) {
        int j0 = adj[t], j1 = adj[t + 1];
        unsigned u0 = *(const unsigned*)(xws + (size_t)j0 * C_DIM + c * 2);
        unsigned u1 = *(const unsigned*)(xws + (size_t)j1 * C_DIM + c * 2);
        s0 += bfu_lo(u0); s1 += bfu_hi(u0);
        t0 += bfu_lo(u1); t1 += bfu_hi(u1);
    }
    if (t < b1) {
        int j = adj[t];
        unsigned u = *(const unsigned*)(xws + (size_t)j * C_DIM + c * 2);
        s0 += bfu_lo(u); s1 += bfu_hi(u);
    }
    s0 += t0; s1 += t1;
    unsigned o = bf16_bits(s0) | (bf16_bits(s1) << 16);
    *(unsigned*)(agg + (size_t)v * C_DIM + c * 2) = o;
}

// ---------------- K6: out[e] = leaky( dinv_e*(agg[src]+xws[e]) + b_gcn ), un-p2
// 8 canonical cols (32B output) per thread; dinv_e coalesced.
__global__ void k_out(const __bf16* __restrict__ xws, const __bf16* __restrict__ agg,
                      const int* __restrict__ src, const float* __restrict__ dinv_e,
                      const float* __restrict__ b_gcn, float* __restrict__ out, int E) {
    int g = blockIdx.x * 256 + threadIdx.x;      // E*16 threads, 8 cols each
    if (g >= E * 16) return;
    int e = g >> 4, c8 = (g & 15) * 8;           // canonical cols c8..c8+7
    int s = src[e];
    float di = dinv_e[e];
    float4 r[2];
#pragma unroll
    for (int h = 0; h < 2; ++h) {
        int c4 = c8 + h * 4;
        int p4 = ((c4 >> 5) & 3) * 32 + ((c4 >> 2) & 3) * 8 + ((c4 >> 4) & 1) * 4;   // p2 position
        uint2 u  = *(const uint2*)(xws + (size_t)e * C_DIM + p4);
        uint2 au = *(const uint2*)(agg + (size_t)s * C_DIM + p4);
        float4 b = *(const float4*)&b_gcn[c4];
        r[h].x = di * (bfu_lo(au.x) + bfu_lo(u.x)) + b.x;
        r[h].y = di * (bfu_hi(au.x) + bfu_hi(u.x)) + b.y;
        r[h].z = di * (bfu_lo(au.y) + bfu_lo(u.y)) + b.z;
        r[h].w = di * (bfu_hi(au.y) + bfu_hi(u.y)) + b.w;
        r[h].x = r[h].x > 0.f ? r[h].x : 0.01f * r[h].x;
        r[h].y = r[h].y > 0.f ? r[h].y : 0.01f * r[h].y;
        r[h].z = r[h].z > 0.f ? r[h].z : 0.01f * r[h].z;
        r[h].w = r[h].w > 0.f ? r[h].w : 0.01f * r[h].w;
        *(float4*)&out[(size_t)e * C_DIM + c4] = r[h];
    }
}

extern "C" void kernel_launch(void* const* d_in, const int* in_sizes, int n_in,
                              void* d_out, int out_size, void* d_ws, size_t ws_size,
                              hipStream_t stream) {
    const float* x      = (const float*)d_in[0];
    const float* ea     = (const float*)d_in[1];
    const float* W_edge = (const float*)d_in[2];
    const float* b_edge = (const float*)d_in[3];
    const float* W_gcn  = (const float*)d_in[4];
    const float* b_gcn  = (const float*)d_in[5];
    const int*   ei     = (const int*)d_in[6];
    // d_in[7] = batch (unused), d_in[8] = line_edge_index (unused)

    const int C  = in_sizes[3];            // 128
    const int Nn = in_sizes[0] / C;        // 50000
    const int E  = in_sizes[1] / C;        // 300000
    const int* srcp = ei;
    const int* dstp = ei + E;

    char* ws = (char*)d_ws;
    size_t off = 0;
    auto alloc = [&](size_t bytes) { size_t o = off; off = (off + bytes + 255) & ~(size_t)255; return o; };
    __bf16* Wf     = (__bf16*)(ws + alloc((size_t)384 * 128 * sizeof(__bf16)));
    float*  b_comb = (float*)(ws + alloc(128 * sizeof(float)));
    int*    indeg  = (int*)(ws + alloc((size_t)Nn * sizeof(int)));
    int*    ptr    = (int*)(ws + alloc((size_t)(Nn + 1) * sizeof(int)));
    int*    cursor = (int*)(ws + alloc((size_t)Nn * sizeof(int)));
    int*    bsum   = (int*)(ws + alloc(64 * sizeof(int)));
    int*    adj    = (int*)(ws + alloc((size_t)E * sizeof(int)));
    float*  dinv_e = (float*)(ws + alloc((size_t)E * sizeof(float)));
    __bf16* P1     = (__bf16*)(ws + alloc((size_t)Nn * C * sizeof(__bf16)));
    __bf16* P2     = (__bf16*)(ws + alloc((size_t)Nn * C * sizeof(__bf16)));
    __bf16* xws    = (__bf16*)(ws + alloc((size_t)E * C * sizeof(__bf16)));
    __bf16* agg    = (__bf16*)(ws + alloc((size_t)Nn * C * sizeof(__bf16)));

    const int nb = (Nn + 1023) / 1024;         // 49
    const int nbE = (E + 255) / 256;           // 1172
    const int nbP = (Nn + 63) / 64;            // 782

    (void)hipMemsetAsync(indeg, 0, (size_t)Nn * sizeof(int), stream);
    k_wcomb_indeg<<<192 + nbE, 256, 0, stream>>>(W_edge, W_gcn, b_edge, Wf, b_comb, dstp, E, indeg);
    k_scan_bsum<<<nb, 1024, 0, stream>>>(indeg, Nn, bsum);
    k_scan_fin<<<nb, 1024, 0, stream>>>(indeg, Nn, bsum, nb, ptr, cursor);
    k_place_p12<<<nbE + nbP, 256, 0, stream>>>(srcp, dstp, E, nbE, cursor, adj, indeg, dinv_e,
                                               x, Wf, b_comb, P1, P2, Nn);
    k_gemm3<<<(E + 255) / 256, 512, 0, stream>>>(ea, Wf, P1, P2, srcp, dstp, dinv_e, xws, E);
    k_agg<<<(Nn + 3) / 4, 256, 0, stream>>>(xws, ptr, adj, agg, Nn);
    k_out<<<(E * 16 + 255) / 256, 256, 0, stream>>>(xws, agg, srcp, dinv_e, b_gcn, (float*)d_out, E);
}

// Round 18
// 203.611 us; speedup vs baseline: 1.0232x; 1.0232x over previous
//
#include <hip/hip_runtime.h>
#include <hip/hip_bf16.h>

// N=50000 nodes, E=300000 edges, C=128.
// W_comb = W_edge@W_gcn = [W1;W2;W3].
//   P1 = x@W1 + b_comb, P2 = x@W2          (bf16, P2-PERMUTED col layout)
//   xws[e] = (ea[e]@W3 + P1[src]+P2[dst]) * dinv_e[e]   (bf16, P2-PERMUTED)
//   agg[v] = sum_{dst(j)=v} xws[j]          (bf16, P2-PERMUTED)
//   out[e] = leaky( dinv_e[e]*(agg[src[e]] + xws[e]) + b_gcn )   (f32, canonical)
// p2(c) = ((c>>5)&3)*32 + ((c>>2)&3)*8 + ((c>>4)&1)*4 + (c&3).
// dinv_e precomputed (coalesced) to cut the src->indeg dependent-load hop.
// R16 best-known configuration (203.8 us).

typedef __bf16 bf16x8 __attribute__((ext_vector_type(8)));
typedef float  f32x4  __attribute__((ext_vector_type(4)));

#define C_DIM 128

__device__ __forceinline__ float bfu_lo(unsigned u) { return __uint_as_float(u << 16); }
__device__ __forceinline__ float bfu_hi(unsigned u) { return __uint_as_float(u & 0xffff0000u); }
__device__ __forceinline__ unsigned bf16_bits(float f) {
    __bf16 h = (__bf16)f;
    return (unsigned)__builtin_bit_cast(unsigned short, h);
}

// ---------------- K0: fused {W_comb fragment build + b_comb} and {in-degree}
__global__ void k_wcomb_indeg(const float* __restrict__ W_edge, const float* __restrict__ W_gcn,
                              const float* __restrict__ b_edge,
                              __bf16* __restrict__ Wf, float* __restrict__ b_comb,
                              const int* __restrict__ dst, int E, int* __restrict__ indeg) {
    if ((int)blockIdx.x < 192) {
        int idx = blockIdx.x * 256 + threadIdx.x;        // 384*128 outputs
        if (idx < 384 * 128) {
            int k = idx >> 7, c = idx & 127;
            float s = 0.f;
            for (int m = 0; m < 128; ++m) s += W_edge[k * 128 + m] * W_gcn[m * 128 + c];
            int ks = k >> 5, kc8 = (k >> 3) & 3, j = k & 7;
            int col16 = c >> 4, c15 = c & 15;
            Wf[(size_t)(((ks * 8 + col16) * 64) + kc8 * 16 + c15) * 8 + j] = (__bf16)s;
        }
        if (blockIdx.x == 0 && threadIdx.x < 128) {
            int c = threadIdx.x;
            float s = 0.f;
            for (int m = 0; m < 128; ++m) s += b_edge[m] * W_gcn[m * 128 + c];
            b_comb[c] = s;
        }
        return;
    }
    int e = ((int)blockIdx.x - 192) * 256 + threadIdx.x;
    if (e < E) atomicAdd(&indeg[dst[e]], 1);
}

// ---------------- K2a: per-block sums of indeg (1024-elem blocks)
__global__ void k_scan_bsum(const int* __restrict__ indeg, int n, int* __restrict__ bsum) {
    __shared__ int ws[16];
    int i = blockIdx.x * 1024 + threadIdx.x;
    int v = (i < n) ? indeg[i] : 0;
    int lane = threadIdx.x & 63, wid = threadIdx.x >> 6;
    for (int off = 32; off; off >>= 1) v += __shfl_down(v, off);
    if (lane == 0) ws[wid] = v;
    __syncthreads();
    if (threadIdx.x < 16) {
        int s = ws[threadIdx.x];
        for (int off = 8; off; off >>= 1) s += __shfl_down(s, off);
        if (threadIdx.x == 0) bsum[blockIdx.x] = s;
    }
}

// ---------------- K2b: finalize exclusive scan (integrates top-level scan of bsum)
__global__ void k_scan_fin(const int* __restrict__ indeg, int n, const int* __restrict__ bsum,
                           int nb, int* __restrict__ ptr, int* __restrict__ cursor) {
    __shared__ int wsum[16];
    __shared__ int s_boff, s_total;
    int lane = threadIdx.x & 63, wid = threadIdx.x >> 6;
    if (threadIdx.x < 64) {
        int v = (lane < nb) ? bsum[lane] : 0;
        int incl = v;
        for (int off = 1; off < 64; off <<= 1) {
            int t = __shfl_up(incl, off);
            if (lane >= off) incl += t;
        }
        if (lane == (int)blockIdx.x) s_boff = incl - v;
        if (lane == 63) s_total = incl;
    }
    int i = blockIdx.x * 1024 + threadIdx.x;
    int v = (i < n) ? indeg[i] : 0;
    int incl = v;
    for (int off = 1; off < 64; off <<= 1) {
        int t = __shfl_up(incl, off);
        if (lane >= off) incl += t;
    }
    if (lane == 63) wsum[wid] = incl;
    __syncthreads();
    if (wid == 0 && lane < 16) {
        int s = wsum[lane];
        for (int off = 1; off < 16; off <<= 1) {
            int t = __shfl_up(s, off);
            if (lane >= off) s += t;
        }
        wsum[lane] = s;
    }
    __syncthreads();
    int woff = wid ? wsum[wid - 1] : 0;
    if (i < n) {
        int ex = s_boff + woff + incl - v;
        ptr[i] = ex;
        cursor[i] = ex;
    }
    if (blockIdx.x == 0 && threadIdx.x == 0) ptr[n] = s_total;
}

// ---------------- K3+K4a fused: {CSR place + dinv_e} and {P1 = x@W1 + b_comb, P2 = x@W2}
__global__ __launch_bounds__(256) void k_place_p12(
    const int* __restrict__ src, const int* __restrict__ dst, int E, int nbPlace,
    int* __restrict__ cursor, int* __restrict__ adj,
    const int* __restrict__ indeg, float* __restrict__ dinv_e,
    const float* __restrict__ x, const __bf16* __restrict__ Wf,
    const float* __restrict__ b_comb,
    __bf16* __restrict__ P1, __bf16* __restrict__ P2, int M) {

    __shared__ __align__(16) __bf16 As[64 * 136];

    if ((int)blockIdx.x < nbPlace) {
        int e = blockIdx.x * 256 + threadIdx.x;
        if (e < E) {
            int pos = atomicAdd(&cursor[dst[e]], 1);
            adj[pos] = e;
            dinv_e[e] = rsqrtf(1.0f + (float)indeg[src[e]]);
        }
        return;
    }

    const int tid = threadIdx.x;
    const int mbase = ((int)blockIdx.x - nbPlace) * 64;
    const int r = tid >> 2, q = tid & 3;
    const int m_r = mbase + r;
    const int m_rc = (m_r < M) ? m_r : 0;
    const float* rp = x + (size_t)m_rc * C_DIM;

#pragma unroll
    for (int s4 = 0; s4 < 4; ++s4) {
        const float* p = rp + s4 * 32 + q * 8;
        float4 f0 = *(const float4*)p;
        float4 f1 = *(const float4*)(p + 4);
        bf16x8 h;
        h[0] = (__bf16)f0.x; h[1] = (__bf16)f0.y; h[2] = (__bf16)f0.z; h[3] = (__bf16)f0.w;
        h[4] = (__bf16)f1.x; h[5] = (__bf16)f1.y; h[6] = (__bf16)f1.z; h[7] = (__bf16)f1.w;
        int u = s4 * 4 + q;                              // 16B unit 0..15
        *(bf16x8*)&As[r * 128 + ((u ^ (r & 7)) << 3)] = h;
    }
    __syncthreads();

    const int lane = tid & 63, wid = tid >> 6;
    const int wr = wid >> 1, wc = wid & 1;
    const int kc8 = lane >> 4;
    const int arow0 = wr * 32 + (lane & 15);
    const int arow1 = arow0 + 16;
    const __bf16* wfb = Wf + ((size_t)(wc * 4) * 64 + lane) * 8;

    f32x4 acc1[2][4] = {};
    f32x4 acc2[2][4] = {};

#pragma unroll
    for (int ks = 0; ks < 4; ++ks) {
        int u = ks * 4 + kc8;
        bf16x8 a0 = *(const bf16x8*)&As[arow0 * 128 + ((u ^ (arow0 & 7)) << 3)];
        bf16x8 a1 = *(const bf16x8*)&As[arow1 * 128 + ((u ^ (arow1 & 7)) << 3)];
#pragma unroll
        for (int n = 0; n < 4; ++n) {
            bf16x8 b1 = *(const bf16x8*)&wfb[(size_t)(ks * 8 + n) * 64 * 8];
            bf16x8 b2 = *(const bf16x8*)&wfb[(size_t)((ks + 4) * 8 + n) * 64 * 8];
            acc1[0][n] = __builtin_amdgcn_mfma_f32_16x16x32_bf16(a0, b1, acc1[0][n], 0, 0, 0);
            acc1[1][n] = __builtin_amdgcn_mfma_f32_16x16x32_bf16(a1, b1, acc1[1][n], 0, 0, 0);
            acc2[0][n] = __builtin_amdgcn_mfma_f32_16x16x32_bf16(a0, b2, acc2[0][n], 0, 0, 0);
            acc2[1][n] = __builtin_amdgcn_mfma_f32_16x16x32_bf16(a1, b2, acc2[1][n], 0, 0, 0);
        }
    }

#pragma unroll
    for (int pass = 0; pass < 2; ++pass) {
        __syncthreads();
#pragma unroll
        for (int m = 0; m < 2; ++m)
#pragma unroll
            for (int j = 0; j < 4; ++j) {
                int row = wr * 32 + m * 16 + (lane >> 4) * 4 + j;
#pragma unroll
                for (int n = 0; n < 4; ++n) {
                    int c = wc * 64 + n * 16 + (lane & 15);
                    // p2(c): unit-transposed permutation
                    int p = ((c >> 5) & 3) * 32 + ((c >> 2) & 3) * 8 + ((c >> 4) & 1) * 4 + (c & 3);
                    float v = pass == 0 ? acc1[m][n][j] + b_comb[c] : acc2[m][n][j];
                    As[row * 136 + p] = (__bf16)v;
                }
            }
        __syncthreads();
        if (m_r < M) {
            __bf16* outp = (pass == 0 ? P1 : P2) + (size_t)m_r * C_DIM + q * 32;
#pragma unroll
            for (int i = 0; i < 4; ++i)
                *(bf16x8*)(outp + i * 8) = *(const bf16x8*)&As[r * 136 + q * 32 + i * 8];
        }
    }
}

// ---------------- K4b: xws[e] = (ea[e]@W3 + P1[src]+P2[dst]) * dinv_e  (p2 layout)
// Swapped-operand, wave-autonomous, 2 staggered tiles/wave, LDS-staged W3.
__global__ __launch_bounds__(256) void k_gemm3(
    const float* __restrict__ ea, const __bf16* __restrict__ Wf,
    const __bf16* __restrict__ P1, const __bf16* __restrict__ P2,
    const int* __restrict__ src, const int* __restrict__ dst,
    const float* __restrict__ dinv_e, __bf16* __restrict__ xws, int E) {

    __shared__ __align__(16) __bf16 Wlds[16384];       // 32KB: frags (ks 0..3)x(n 0..7)

    const int tid = threadIdx.x;
    // ---- W-stage first (L2-hot 32KB), one fast barrier
    {
        const uint4* wsrc = (const uint4*)Wf + 4096;    // ksAbs 8..11 slice
        uint4* wdst = (uint4*)Wlds;
#pragma unroll
        for (int i = 0; i < 8; ++i) wdst[tid + i * 256] = wsrc[tid + i * 256];
    }
    __syncthreads();

    const int wid = tid >> 6, lane = tid & 63;
    const int e15 = lane & 15, q = lane >> 4;
    const int eb0 = blockIdx.x * 128 + wid * 32;
    const int eb1 = eb0 + 16;
    if (eb0 >= E) return;
    const bool has1 = (eb1 < E);

    const int e0 = eb0 + e15;
    const int e0c = (e0 < E) ? e0 : E - 1;
    const int e1 = eb1 + e15;
    const int e1c = (e1 < E) ? e1 : E - 1;

    // ---- indices + dinv (both tiles); dinv_e is a coalesced load
    const int s0 = src[e0c], d0 = dst[e0c];
    const float di0 = dinv_e[e0c];
    int s1 = s0, d1 = d0;
    float di1 = di0;
    if (has1) { s1 = src[e1c]; d1 = dst[e1c]; di1 = dinv_e[e1c]; }

    // ---- issue ea0, P0, ea1
    const float* ap0 = ea + (size_t)e0c * C_DIM + q * 8;
    float4 fa[8];
#pragma unroll
    for (int ks = 0; ks < 4; ++ks) {
        fa[2 * ks]     = *(const float4*)(ap0 + ks * 32);
        fa[2 * ks + 1] = *(const float4*)(ap0 + ks * 32 + 4);
    }
    // p2 layout: unit m of this lane at elem q*8 + m*32 (one full 64B line/instr)
    uint4 hA1[4], hA2[4];
    {
        const uint4* p1 = (const uint4*)(P1 + (size_t)s0 * C_DIM + q * 8);
        const uint4* p2 = (const uint4*)(P2 + (size_t)d0 * C_DIM + q * 8);
#pragma unroll
        for (int m = 0; m < 4; ++m) { hA1[m] = p1[m * 4]; hA2[m] = p2[m * 4]; }
    }
    const float* ap1 = ea + (size_t)e1c * C_DIM + q * 8;
    float4 fb[8];
    if (has1) {
#pragma unroll
        for (int ks = 0; ks < 4; ++ks) {
            fb[2 * ks]     = *(const float4*)(ap1 + ks * 32);
            fb[2 * ks + 1] = *(const float4*)(ap1 + ks * 32 + 4);
        }
    }

    // ---- tile0 MFMA
    f32x4 acc[8] = {};
#pragma unroll
    for (int ks = 0; ks < 4; ++ks) {
        float4 f0 = fa[2 * ks], f1 = fa[2 * ks + 1];
        bf16x8 b;
        b[0] = (__bf16)f0.x; b[1] = (__bf16)f0.y; b[2] = (__bf16)f0.z; b[3] = (__bf16)f0.w;
        b[4] = (__bf16)f1.x; b[5] = (__bf16)f1.y; b[6] = (__bf16)f1.z; b[7] = (__bf16)f1.w;
#pragma unroll
        for (int n = 0; n < 8; ++n) {
            bf16x8 a = *(const bf16x8*)&Wlds[(size_t)((ks * 8 + n) * 64 + lane) * 8];
            acc[n] = __builtin_amdgcn_mfma_f32_16x16x32_bf16(a, b, acc[n], 0, 0, 0);
        }
    }

    // ---- issue P gathers for tile1 (hide under epilogue0 + mfma1)
    uint4 hB1[4], hB2[4];
    if (has1) {
        const uint4* p1 = (const uint4*)(P1 + (size_t)s1 * C_DIM + q * 8);
        const uint4* p2 = (const uint4*)(P2 + (size_t)d1 * C_DIM + q * 8);
#pragma unroll
        for (int m = 0; m < 4; ++m) { hB1[m] = p1[m * 4]; hB2[m] = p2[m * 4]; }
    }

    // ---- epilogue0 (p2 layout: unit m stored at elem q*8 + m*32)
    if (e0 < E) {
        __bf16* op = xws + (size_t)e0 * C_DIM + q * 8;
#pragma unroll
        for (int m = 0; m < 4; ++m) {
            bf16x8 h1 = __builtin_bit_cast(bf16x8, hA1[m]);
            bf16x8 h2 = __builtin_bit_cast(bf16x8, hA2[m]);
            uint4 u;
            unsigned w[4];
#pragma unroll
            for (int hw = 0; hw < 4; ++hw) {
                int n = 2 * m + (hw >> 1);
                int j0 = (hw & 1) * 2;
                float v0 = (acc[n][j0]     + (float)h1[(hw >> 1) * 4 + j0]     + (float)h2[(hw >> 1) * 4 + j0])     * di0;
                float v1 = (acc[n][j0 + 1] + (float)h1[(hw >> 1) * 4 + j0 + 1] + (float)h2[(hw >> 1) * 4 + j0 + 1]) * di0;
                w[hw] = bf16_bits(v0) | (bf16_bits(v1) << 16);
            }
            u.x = w[0]; u.y = w[1]; u.z = w[2]; u.w = w[3];
            *(uint4*)(op + m * 32) = u;
        }
    }

    if (!has1) return;

    // ---- tile1 MFMA
    f32x4 acc2[8] = {};
#pragma unroll
    for (int ks = 0; ks < 4; ++ks) {
        float4 f0 = fb[2 * ks], f1 = fb[2 * ks + 1];
        bf16x8 b;
        b[0] = (__bf16)f0.x; b[1] = (__bf16)f0.y; b[2] = (__bf16)f0.z; b[3] = (__bf16)f0.w;
        b[4] = (__bf16)f1.x; b[5] = (__bf16)f1.y; b[6] = (__bf16)f1.z; b[7] = (__bf16)f1.w;
#pragma unroll
        for (int n = 0; n < 8; ++n) {
            bf16x8 a = *(const bf16x8*)&Wlds[(size_t)((ks * 8 + n) * 64 + lane) * 8];
            acc2[n] = __builtin_amdgcn_mfma_f32_16x16x32_bf16(a, b, acc2[n], 0, 0, 0);
        }
    }

    // ---- epilogue1
    if (e1 < E) {
        __bf16* op = xws + (size_t)e1 * C_DIM + q * 8;
#pragma unroll
        for (int m = 0; m < 4; ++m) {
            bf16x8 h1 = __builtin_bit_cast(bf16x8, hB1[m]);
            bf16x8 h2 = __builtin_bit_cast(bf16x8, hB2[m]);
            uint4 u;
            unsigned w[4];
#pragma unroll
            for (int hw = 0; hw < 4; ++hw) {
                int n = 2 * m + (hw >> 1);
                int j0 = (hw & 1) * 2;
                float v0 = (acc2[n][j0]     + (float)h1[(hw >> 1) * 4 + j0]     + (float)h2[(hw >> 1) * 4 + j0])     * di1;
                float v1 = (acc2[n][j0 + 1] + (float)h1[(hw >> 1) * 4 + j0 + 1] + (float)h2[(hw >> 1) * 4 + j0 + 1]) * di1;
                w[hw] = bf16_bits(v0) | (bf16_bits(v1) << 16);
            }
            u.x = w[0]; u.y = w[1]; u.z = w[2]; u.w = w[3];
            *(uint4*)(op + m * 32) = u;
        }
    }
}

// ---------------- K5: agg[v] = sum over incoming edges (unroll-2, layout-agnostic)
__global__ void k_agg(const __bf16* __restrict__ xws, const int* __restrict__ ptr,
                      const int* __restrict__ adj, __bf16* __restrict__ agg, int Nn) {
    int v = blockIdx.x * 4 + (threadIdx.x >> 6);
    if (v >= Nn) return;
    int c = threadIdx.x & 63;           // permuted positions 2c / 2c+1
    int b0 = ptr[v], b1 = ptr[v + 1];
    float s0 = 0.f, s1 = 0.f, t0 = 0.f, t1 = 0.f;
    int t = b0;
    for (; t + 2 <= b1; t += 2) {
        int j0 = adj[t], j1 = adj[t + 1];
        unsigned u0 = *(const unsigned*)(xws + (size_t)j0 * C_DIM + c * 2);
        unsigned u1 = *(const unsigned*)(xws + (size_t)j1 * C_DIM + c * 2);
        s0 += bfu_lo(u0); s1 += bfu_hi(u0);
        t0 += bfu_lo(u1); t1 += bfu_hi(u1);
    }
    if (t < b1) {
        int j = adj[t];
        unsigned u = *(const unsigned*)(xws + (size_t)j * C_DIM + c * 2);
        s0 += bfu_lo(u); s1 += bfu_hi(u);
    }
    s0 += t0; s1 += t1;
    unsigned o = bf16_bits(s0) | (bf16_bits(s1) << 16);
    *(unsigned*)(agg + (size_t)v * C_DIM + c * 2) = o;
}

// ---------------- K6: out[e] = leaky( dinv_e*(agg[src]+xws[e]) + b_gcn ), un-p2
// 8 canonical cols (32B output) per thread; dinv_e coalesced.
__global__ void k_out(const __bf16* __restrict__ xws, const __bf16* __restrict__ agg,
                      const int* __restrict__ src, const float* __restrict__ dinv_e,
                      const float* __restrict__ b_gcn, float* __restrict__ out, int E) {
    int g = blockIdx.x * 256 + threadIdx.x;      // E*16 threads, 8 cols each
    if (g >= E * 16) return;
    int e = g >> 4, c8 = (g & 15) * 8;           // canonical cols c8..c8+7
    int s = src[e];
    float di = dinv_e[e];
    float4 r[2];
#pragma unroll
    for (int h = 0; h < 2; ++h) {
        int c4 = c8 + h * 4;
        int p4 = ((c4 >> 5) & 3) * 32 + ((c4 >> 2) & 3) * 8 + ((c4 >> 4) & 1) * 4;   // p2 position
        uint2 u  = *(const uint2*)(xws + (size_t)e * C_DIM + p4);
        uint2 au = *(const uint2*)(agg + (size_t)s * C_DIM + p4);
        float4 b = *(const float4*)&b_gcn[c4];
        r[h].x = di * (bfu_lo(au.x) + bfu_lo(u.x)) + b.x;
        r[h].y = di * (bfu_hi(au.x) + bfu_hi(u.x)) + b.y;
        r[h].z = di * (bfu_lo(au.y) + bfu_lo(u.y)) + b.z;
        r[h].w = di * (bfu_hi(au.y) + bfu_hi(u.y)) + b.w;
        r[h].x = r[h].x > 0.f ? r[h].x : 0.01f * r[h].x;
        r[h].y = r[h].y > 0.f ? r[h].y : 0.01f * r[h].y;
        r[h].z = r[h].z > 0.f ? r[h].z : 0.01f * r[h].z;
        r[h].w = r[h].w > 0.f ? r[h].w : 0.01f * r[h].w;
        *(float4*)&out[(size_t)e * C_DIM + c4] = r[h];
    }
}

extern "C" void kernel_launch(void* const* d_in, const int* in_sizes, int n_in,
                              void* d_out, int out_size, void* d_ws, size_t ws_size,
                              hipStream_t stream) {
    const float* x      = (const float*)d_in[0];
    const float* ea     = (const float*)d_in[1];
    const float* W_edge = (const float*)d_in[2];
    const float* b_edge = (const float*)d_in[3];
    const float* W_gcn  = (const float*)d_in[4];
    const float* b_gcn  = (const float*)d_in[5];
    const int*   ei     = (const int*)d_in[6];
    // d_in[7] = batch (unused), d_in[8] = line_edge_index (unused)

    const int C  = in_sizes[3];            // 128
    const int Nn = in_sizes[0] / C;        // 50000
    const int E  = in_sizes[1] / C;        // 300000
    const int* srcp = ei;
    const int* dstp = ei + E;

    char* ws = (char*)d_ws;
    size_t off = 0;
    auto alloc = [&](size_t bytes) { size_t o = off; off = (off + bytes + 255) & ~(size_t)255; return o; };
    __bf16* Wf     = (__bf16*)(ws + alloc((size_t)384 * 128 * sizeof(__bf16)));
    float*  b_comb = (float*)(ws + alloc(128 * sizeof(float)));
    int*    indeg  = (int*)(ws + alloc((size_t)Nn * sizeof(int)));
    int*    ptr    = (int*)(ws + alloc((size_t)(Nn + 1) * sizeof(int)));
    int*    cursor = (int*)(ws + alloc((size_t)Nn * sizeof(int)));
    int*    bsum   = (int*)(ws + alloc(64 * sizeof(int)));
    int*    adj    = (int*)(ws + alloc((size_t)E * sizeof(int)));
    float*  dinv_e = (float*)(ws + alloc((size_t)E * sizeof(float)));
    __bf16* P1     = (__bf16*)(ws + alloc((size_t)Nn * C * sizeof(__bf16)));
    __bf16* P2     = (__bf16*)(ws + alloc((size_t)Nn * C * sizeof(__bf16)));
    __bf16* xws    = (__bf16*)(ws + alloc((size_t)E * C * sizeof(__bf16)));
    __bf16* agg    = (__bf16*)(ws + alloc((size_t)Nn * C * sizeof(__bf16)));

    const int nb = (Nn + 1023) / 1024;         // 49
    const int nbE = (E + 255) / 256;           // 1172
    const int nbP = (Nn + 63) / 64;            // 782

    (void)hipMemsetAsync(indeg, 0, (size_t)Nn * sizeof(int), stream);
    k_wcomb_indeg<<<192 + nbE, 256, 0, stream>>>(W_edge, W_gcn, b_edge, Wf, b_comb, dstp, E, indeg);
    k_scan_bsum<<<nb, 1024, 0, stream>>>(indeg, Nn, bsum);
    k_scan_fin<<<nb, 1024, 0, stream>>>(indeg, Nn, bsum, nb, ptr, cursor);
    k_place_p12<<<nbE + nbP, 256, 0, stream>>>(srcp, dstp, E, nbE, cursor, adj, indeg, dinv_e,
                                               x, Wf, b_comb, P1, P2, Nn);
    k_gemm3<<<(E + 127) / 128, 256, 0, stream>>>(ea, Wf, P1, P2, srcp, dstp, dinv_e, xws, E);
    k_agg<<<(Nn + 3) / 4, 256, 0, stream>>>(xws, ptr, adj, agg, Nn);
    k_out<<<(E * 16 + 255) / 256, 256, 0, stream>>>(xws, agg, srcp, dinv_e, b_gcn, (float*)d_out, E);
}